// Round 2
// baseline (554.366 us; speedup 1.0000x reference)
//
#include <hip/hip_runtime.h>

// ---------------------------------------------------------------------------
// RPN head on gfx950: x --conv3x3(512->256)+relu--> h1 --conv3x3(256->256)+relu
//   --> h2 --1x1 heads (cls 18 / reg 36)--> softmax pairs --> out (B,H,W,9,6)
// Strategy: bf16 MFMA implicit GEMM (16x16x32), padded input halo, B^T weights.
// R1 fix: heads LDS staging used 16 segs/row instead of 32 -> k=128..255 of As
// was uninitialized LDS -> NaN. Also zero WhT pad rows (54..63) via memset.
// ---------------------------------------------------------------------------

typedef float f32x4 __attribute__((ext_vector_type(4)));
typedef short bf16x8 __attribute__((ext_vector_type(8)));   // 8 bf16 = 4 VGPRs

union U16x8 { uint4 v; unsigned short s[8]; };

__device__ __forceinline__ unsigned short f2bf(float f) {
  union { float f; unsigned int u; } v; v.f = f;
  unsigned int r = v.u + 0x7FFFu + ((v.u >> 16) & 1u);   // RNE
  return (unsigned short)(r >> 16);
}

// ---- transpose + fp32->bf16: src[z][K][N] -> dst[z][N][K] ------------------
__global__ __launch_bounds__(256) void transpose_cvt(
    const float* __restrict__ src, unsigned short* __restrict__ dst,
    int K, int N) {
  __shared__ float t[32][33];
  const int tx = threadIdx.x, ty = threadIdx.y;     // 32 x 8
  const int k0 = blockIdx.x * 32, n0 = blockIdx.y * 32;
  const float* s = src + (size_t)blockIdx.z * K * N;
  unsigned short* d = dst + (size_t)blockIdx.z * N * K;
#pragma unroll
  for (int r = 0; r < 32; r += 8) {
    int k = k0 + ty + r, n = n0 + tx;
    t[ty + r][tx] = (k < K && n < N) ? s[(size_t)k * N + n] : 0.f;
  }
  __syncthreads();
#pragma unroll
  for (int r = 0; r < 32; r += 8) {
    int n = n0 + ty + r, k = k0 + tx;
    if (n < N && k < K) d[(size_t)n * K + k] = f2bf(t[tx][ty + r]);
  }
}

// ---- x (f32 NHWC) -> x_pad (bf16, [4][130][130][512], zero halo) -----------
__global__ __launch_bounds__(256) void convert_x(
    const float* __restrict__ x, unsigned short* __restrict__ xp) {
  int idx = blockIdx.x * 256 + threadIdx.x;       // 4*130*130*64 exactly
  int g = idx & 63;                                // 8-channel group
  int cell = idx >> 6;
  int xpix = cell % 130;
  int t = cell / 130;
  int ypix = t % 130;
  int b = t / 130;
  U16x8 u;
  if (xpix == 0 || xpix == 129 || ypix == 0 || ypix == 129) {
    u.v = make_uint4(0u, 0u, 0u, 0u);
  } else {
    const float* sp = x + ((size_t)((b * 128 + ypix - 1) * 128) + (xpix - 1)) * 512 + g * 8;
    float4 a = *(const float4*)sp;
    float4 c = *(const float4*)(sp + 4);
    u.s[0] = f2bf(a.x); u.s[1] = f2bf(a.y); u.s[2] = f2bf(a.z); u.s[3] = f2bf(a.w);
    u.s[4] = f2bf(c.x); u.s[5] = f2bf(c.y); u.s[6] = f2bf(c.z); u.s[7] = f2bf(c.w);
  }
  *(uint4*)(xp + (size_t)cell * 512 + g * 8) = u.v;
}

// ---- zero the halo of h1_pad ([4][130][130][256]) --------------------------
__global__ __launch_bounds__(256) void zero_h1_borders(unsigned short* __restrict__ h1p) {
  int idx = blockIdx.x * 256 + threadIdx.x;       // 4*130*130*32 exactly
  int g = idx & 31;
  int cell = idx >> 5;
  int xpix = cell % 130;
  int t = cell / 130;
  int ypix = t % 130;
  if (xpix == 0 || xpix == 129 || ypix == 0 || ypix == 129)
    *(uint4*)(h1p + (size_t)cell * 256 + g * 8) = make_uint4(0u, 0u, 0u, 0u);
}

// ---- 3x3 conv as implicit GEMM, bf16 MFMA 16x16x32 -------------------------
// Ap:  [4][130][130][CIN] bf16 (zero halo).  WT: [9][256][CIN] bf16 (B^T).
// MODE 0: out = h1_pad [4][130][130][256] (write interior).  MODE 1: flat.
// Tile: BM=128 (one image row), BN=128 (blockIdx.y half of co), BK=64.
// 256 threads = 4 waves in 2x2; each wave 64x64 = 4x4 frags of 16x16.
template<int CIN, int MODE>
__global__ __launch_bounds__(256) void conv3x3(
    const unsigned short* __restrict__ Ap,
    const unsigned short* __restrict__ WT,
    const float* __restrict__ bias,
    unsigned short* __restrict__ out) {
  // +8 pad -> row stride 36 dwords: b128 reads hit the 8-phase floor, no conflicts
  __shared__ __align__(16) unsigned short As[128][72];
  __shared__ __align__(16) unsigned short Bs[128][72];
  const int tid  = threadIdx.x;
  const int wave = tid >> 6, lane = tid & 63;
  const int wm = wave >> 1, wn = wave & 1;
  const int quad = lane >> 4, l16 = lane & 15;
  const int b = blockIdx.x >> 7, y = blockIdx.x & 127;
  const int nbase = blockIdx.y * 128;

  f32x4 acc[4][4] = {};

  for (int tap = 0; tap < 9; ++tap) {
    const int dy = tap / 3, dx = tap % 3;
    const unsigned short* Abase = Ap + ((size_t)(b * 130 + y + dy) * 130 + dx) * CIN;
    const unsigned short* Bbase = WT + ((size_t)tap * 256 + nbase) * CIN;
    for (int ci0 = 0; ci0 < CIN; ci0 += 64) {
#pragma unroll
      for (int r = 0; r < 4; ++r) {
        int s = r * 256 + tid;
        int row = s >> 3, seg = s & 7;              // 128 rows x 8 x 16B
        uint4 va = *(const uint4*)(Abase + (size_t)row * CIN + ci0 + seg * 8);
        *(uint4*)&As[row][seg * 8] = va;
        uint4 vb = *(const uint4*)(Bbase + (size_t)row * CIN + ci0 + seg * 8);
        *(uint4*)&Bs[row][seg * 8] = vb;
      }
      __syncthreads();
#pragma unroll
      for (int ks = 0; ks < 2; ++ks) {
        bf16x8 af[4], bfr[4];
#pragma unroll
        for (int i = 0; i < 4; ++i)
          af[i] = *(const bf16x8*)&As[wm * 64 + i * 16 + l16][ks * 32 + quad * 8];
#pragma unroll
        for (int j = 0; j < 4; ++j)
          bfr[j] = *(const bf16x8*)&Bs[wn * 64 + j * 16 + l16][ks * 32 + quad * 8];
#pragma unroll
        for (int i = 0; i < 4; ++i)
#pragma unroll
          for (int j = 0; j < 4; ++j)
            acc[i][j] = __builtin_amdgcn_mfma_f32_16x16x32_bf16(af[i], bfr[j], acc[i][j], 0, 0, 0);
      }
      __syncthreads();
    }
  }

  // epilogue: D layout row = quad*4+reg (pixel), col = l16 (co). bias+relu->bf16
#pragma unroll
  for (int i = 0; i < 4; ++i) {
#pragma unroll
    for (int j = 0; j < 4; ++j) {
#pragma unroll
      for (int r = 0; r < 4; ++r) {
        int m = wm * 64 + i * 16 + quad * 4 + r;     // pixel x within row
        int n = nbase + wn * 64 + j * 16 + l16;      // output channel
        float v = acc[i][j][r] + bias[n];
        v = fmaxf(v, 0.f);
        size_t off;
        if (MODE == 0)
          off = ((size_t)(b * 130 + y + 1) * 130 + (m + 1)) * 256 + n;
        else
          off = ((size_t)((b * 128 + y) * 128 + m)) * 256 + n;
        out[off] = f2bf(v);
      }
    }
  }
}

// ---- heads: h2[65536][256] x WhT[54(pad 64)][256] + bias, softmax pairs ----
__global__ __launch_bounds__(256) void heads_kernel(
    const unsigned short* __restrict__ h2,
    const unsigned short* __restrict__ WhT,
    const float* __restrict__ br, const float* __restrict__ bc,
    float* __restrict__ out) {
  __shared__ __align__(16) unsigned short As[64][264];
  const int tid = threadIdx.x;
  const int wave = tid >> 6, lane = tid & 63;
  const int quad = lane >> 4, l16 = lane & 15;
  const int pix0 = blockIdx.x * 64;
  // stage 64 rows x 256 halfs = 64 x 32 uint4 segs = 2048 stores (256 thr x 8)
#pragma unroll
  for (int r = 0; r < 8; ++r) {
    int s = r * 256 + tid;
    int row = s >> 5, seg = s & 31;                  // FIX: 32 segs per row
    *(uint4*)&As[row][seg * 8] =
        *(const uint4*)(h2 + (size_t)(pix0 + row) * 256 + seg * 8);
  }
  __syncthreads();
  f32x4 acc[4] = {};
#pragma unroll
  for (int ks = 0; ks < 8; ++ks) {
    bf16x8 af = *(const bf16x8*)&As[wave * 16 + l16][ks * 32 + quad * 8];
#pragma unroll
    for (int j = 0; j < 4; ++j) {
      bf16x8 bfr = *(const bf16x8*)(WhT + (size_t)(j * 16 + l16) * 256 + ks * 32 + quad * 8);
      acc[j] = __builtin_amdgcn_mfma_f32_16x16x32_bf16(af, bfr, acc[j], 0, 0, 0);
    }
  }
#pragma unroll
  for (int j = 0; j < 4; ++j) {
    int n = j * 16 + l16;                            // head channel (cls 0-17, reg 18-53)
    float bias = 0.f;
    if (n < 18) bias = bc[n];
    else if (n < 54) bias = br[n - 18];
#pragma unroll
    for (int r = 0; r < 4; ++r) {
      int p = pix0 + wave * 16 + quad * 4 + r;       // pixel
      float v = acc[j][r] + bias;
      float partner = __shfl_xor(v, 1);              // cls pair (even,odd lanes)
      if (n < 18) {
        float mx = fmaxf(v, partner);
        float e0 = __expf(v - mx), e1 = __expf(partner - mx);
        int a = n >> 1, sl = n & 1;
        out[(size_t)p * 54 + a * 6 + sl] = e0 / (e0 + e1);
      } else if (n < 54) {
        int rr = n - 18, a = rr >> 2, sl = (rr & 3) + 2;
        out[(size_t)p * 54 + a * 6 + sl] = v;
      }
    }
  }
}

// ---------------------------------------------------------------------------
extern "C" void kernel_launch(void* const* d_in, const int* in_sizes, int n_in,
                              void* d_out, int out_size, void* d_ws, size_t ws_size,
                              hipStream_t stream) {
  const float* x  = (const float*)d_in[0];
  const float* W1 = (const float*)d_in[1];
  const float* b1 = (const float*)d_in[2];
  const float* W2 = (const float*)d_in[3];
  const float* b2 = (const float*)d_in[4];
  const float* Wr = (const float*)d_in[5];
  const float* br = (const float*)d_in[6];
  const float* Wc = (const float*)d_in[7];
  const float* bc = (const float*)d_in[8];
  float* out = (float*)d_out;

  // workspace carve-up (bytes)
  constexpr size_t XPAD_B  = 4ull * 130 * 130 * 512 * 2;   //  69,222,400
  constexpr size_t H1PAD_B = 4ull * 130 * 130 * 256 * 2;   //  34,611,200
  constexpr size_t H2_B    = 4ull * 128 * 128 * 256 * 2;   //  33,554,432
  constexpr size_t W1T_B   = 9ull * 256 * 512 * 2;         //   2,359,296
  constexpr size_t W2T_B   = 9ull * 256 * 256 * 2;         //   1,179,648
  char* ws = (char*)d_ws;
  unsigned short* x_pad  = (unsigned short*)(ws);
  unsigned short* h1_pad = (unsigned short*)(ws + XPAD_B);
  unsigned short* h2     = (unsigned short*)(ws + XPAD_B + H1PAD_B);
  unsigned short* W1T    = (unsigned short*)(ws + XPAD_B + H1PAD_B + H2_B);
  unsigned short* W2T    = (unsigned short*)(ws + XPAD_B + H1PAD_B + H2_B + W1T_B);
  unsigned short* WhT    = (unsigned short*)(ws + XPAD_B + H1PAD_B + H2_B + W1T_B + W2T_B);

  // zero the padded head-weight block (rows 54..63 are read by MFMA)
  hipMemsetAsync(WhT, 0, 64ull * 256 * 2, stream);
  // weight repacks (B^T, bf16)
  transpose_cvt<<<dim3(16, 8, 9), dim3(32, 8), 0, stream>>>(W1, W1T, 512, 256);
  transpose_cvt<<<dim3(8, 8, 9),  dim3(32, 8), 0, stream>>>(W2, W2T, 256, 256);
  transpose_cvt<<<dim3(8, 1, 1),  dim3(32, 8), 0, stream>>>(Wc, WhT, 256, 18);
  transpose_cvt<<<dim3(8, 2, 1),  dim3(32, 8), 0, stream>>>(Wr, WhT + 18 * 256, 256, 36);
  // input pad+convert, h1 halo zero
  convert_x<<<16900, 256, 0, stream>>>(x, x_pad);
  zero_h1_borders<<<8450, 256, 0, stream>>>(h1_pad);
  // conv1: 512x130x130 bf16 -> h1_pad ; conv2: -> h2 flat
  conv3x3<512, 0><<<dim3(512, 2), 256, 0, stream>>>(x_pad, W1T, b1, h1_pad);
  conv3x3<256, 1><<<dim3(512, 2), 256, 0, stream>>>(h1_pad, W2T, b2, h2);
  // 1x1 heads + softmax + interleave
  heads_kernel<<<1024, 256, 0, stream>>>(h2, WhT, br, bc, out);
}

// Round 3
// 511.668 us; speedup vs baseline: 1.0834x; 1.0834x over previous
//
#include <hip/hip_runtime.h>

// ---------------------------------------------------------------------------
// RPN head on gfx950: x --conv3x3(512->256)+relu--> h1 --conv3x3(256->256)+relu
//   --> h2 --1x1 heads (cls 18 / reg 36)--> softmax pairs --> out (B,H,W,9,6)
// bf16 MFMA implicit GEMM. R2: dy-row staging with dx-merge (72->24 barrier
// iters, 3x less A traffic) + 32x32x16 MFMA (half the LDS bytes per FLOP).
// ---------------------------------------------------------------------------

typedef float f32x4  __attribute__((ext_vector_type(4)));
typedef float f32x16 __attribute__((ext_vector_type(16)));
typedef short bf16x8 __attribute__((ext_vector_type(8)));   // 8 bf16 = 4 VGPRs

union U16x8 { uint4 v; unsigned short s[8]; };

__device__ __forceinline__ unsigned short f2bf(float f) {
  union { float f; unsigned int u; } v; v.f = f;
  unsigned int r = v.u + 0x7FFFu + ((v.u >> 16) & 1u);   // RNE
  return (unsigned short)(r >> 16);
}

// ---- transpose + fp32->bf16: src[z][K][N] -> dst[z][N][K] ------------------
__global__ __launch_bounds__(256) void transpose_cvt(
    const float* __restrict__ src, unsigned short* __restrict__ dst,
    int K, int N) {
  __shared__ float t[32][33];
  const int tx = threadIdx.x, ty = threadIdx.y;     // 32 x 8
  const int k0 = blockIdx.x * 32, n0 = blockIdx.y * 32;
  const float* s = src + (size_t)blockIdx.z * K * N;
  unsigned short* d = dst + (size_t)blockIdx.z * N * K;
#pragma unroll
  for (int r = 0; r < 32; r += 8) {
    int k = k0 + ty + r, n = n0 + tx;
    t[ty + r][tx] = (k < K && n < N) ? s[(size_t)k * N + n] : 0.f;
  }
  __syncthreads();
#pragma unroll
  for (int r = 0; r < 32; r += 8) {
    int n = n0 + ty + r, k = k0 + tx;
    if (n < N && k < K) d[(size_t)n * K + k] = f2bf(t[tx][ty + r]);
  }
}

// ---- x (f32 NHWC) -> x_pad (bf16, [4][130][130][512], zero halo) -----------
__global__ __launch_bounds__(256) void convert_x(
    const float* __restrict__ x, unsigned short* __restrict__ xp) {
  int idx = blockIdx.x * 256 + threadIdx.x;       // 4*130*130*64 exactly
  int g = idx & 63;                                // 8-channel group
  int cell = idx >> 6;
  int xpix = cell % 130;
  int t = cell / 130;
  int ypix = t % 130;
  int b = t / 130;
  U16x8 u;
  if (xpix == 0 || xpix == 129 || ypix == 0 || ypix == 129) {
    u.v = make_uint4(0u, 0u, 0u, 0u);
  } else {
    const float* sp = x + ((size_t)((b * 128 + ypix - 1) * 128) + (xpix - 1)) * 512 + g * 8;
    float4 a = *(const float4*)sp;
    float4 c = *(const float4*)(sp + 4);
    u.s[0] = f2bf(a.x); u.s[1] = f2bf(a.y); u.s[2] = f2bf(a.z); u.s[3] = f2bf(a.w);
    u.s[4] = f2bf(c.x); u.s[5] = f2bf(c.y); u.s[6] = f2bf(c.z); u.s[7] = f2bf(c.w);
  }
  *(uint4*)(xp + (size_t)cell * 512 + g * 8) = u.v;
}

// ---- zero the halo of h1_pad ([4][130][130][256]) --------------------------
__global__ __launch_bounds__(256) void zero_h1_borders(unsigned short* __restrict__ h1p) {
  int idx = blockIdx.x * 256 + threadIdx.x;       // 4*130*130*32 exactly
  int g = idx & 31;
  int cell = idx >> 5;
  int xpix = cell % 130;
  int t = cell / 130;
  int ypix = t % 130;
  if (xpix == 0 || xpix == 129 || ypix == 0 || ypix == 129)
    *(uint4*)(h1p + (size_t)cell * 256 + g * 8) = make_uint4(0u, 0u, 0u, 0u);
}

// ---- 3x3 conv as implicit GEMM, bf16 MFMA 32x32x16, dx-merged --------------
// Ap:  [4][130][130][CIN] bf16 (zero halo).  WT: [9][256][CIN] bf16 (B^T).
// MODE 0: out = h1_pad [4][130][130][256] (interior).  MODE 1: flat NHWC.
// BM=128 (one image row), BN=128, BK=64. Per (dy, ci0): stage the full padded
// pixel row (130 px) once; dx taps 0..2 read it at +dx. 96 MFMA per barrier.
// 256 thr = 4 waves in 2x2; wave tile 64x64 = 2x2 MFMAs of 32x32.
template<int CIN, int MODE>
__global__ __launch_bounds__(256) void conv3x3(
    const unsigned short* __restrict__ Ap,
    const unsigned short* __restrict__ WT,
    const float* __restrict__ bias,
    unsigned short* __restrict__ out) {
  __shared__ __align__(16) unsigned short As[130][72];     // 18,720 B
  __shared__ __align__(16) unsigned short Bs[3][128][72];  // 55,296 B
  const int tid  = threadIdx.x;
  const int wave = tid >> 6, lane = tid & 63;
  const int wm = wave >> 1, wn = wave & 1;
  const int l31 = lane & 31, hi = lane >> 5;
  const int b = blockIdx.x >> 7, y = blockIdx.x & 127;
  const int nbase = blockIdx.y * 128;

  f32x16 acc[2][2] = {};

  for (int dy = 0; dy < 3; ++dy) {
    const unsigned short* Arow = Ap + ((size_t)(b * 130 + y + dy) * 130) * CIN;
    const unsigned short* Btap = WT + ((size_t)(dy * 3) * 256 + nbase) * CIN;
    for (int ci0 = 0; ci0 < CIN; ci0 += 64) {
      // stage A: 130 pixels x 8 segs of 16B  (1040 uint4)
      for (int s = tid; s < 1040; s += 256) {
        int row = s >> 3, seg = s & 7;
        *(uint4*)&As[row][seg * 8] =
            *(const uint4*)(Arow + (size_t)row * CIN + ci0 + seg * 8);
      }
      // stage B: 3 taps x 128 co x 8 segs (3072 uint4, 12/thread)
#pragma unroll
      for (int t = 0; t < 12; ++t) {
        int s = t * 256 + tid;
        int dx = s >> 10, r = (s >> 3) & 127, seg = s & 7;
        *(uint4*)&Bs[dx][r][seg * 8] =
            *(const uint4*)(Btap + ((size_t)dx * 256 + r) * CIN + ci0 + seg * 8);
      }
      __syncthreads();
#pragma unroll
      for (int dx = 0; dx < 3; ++dx) {
#pragma unroll
        for (int ks = 0; ks < 4; ++ks) {             // K=16 sub-steps of BK=64
          bf16x8 af[2], bfr[2];
#pragma unroll
          for (int i = 0; i < 2; ++i)
            af[i] = *(const bf16x8*)&As[wm * 64 + i * 32 + l31 + dx][ks * 16 + hi * 8];
#pragma unroll
          for (int j = 0; j < 2; ++j)
            bfr[j] = *(const bf16x8*)&Bs[dx][wn * 64 + j * 32 + l31][ks * 16 + hi * 8];
#pragma unroll
          for (int i = 0; i < 2; ++i)
#pragma unroll
            for (int j = 0; j < 2; ++j)
              acc[i][j] = __builtin_amdgcn_mfma_f32_32x32x16_bf16(af[i], bfr[j], acc[i][j], 0, 0, 0);
        }
      }
      __syncthreads();
    }
  }

  // epilogue: 32x32 C/D layout: col = lane&31, row = (reg&3)+8*(reg>>2)+4*hi
#pragma unroll
  for (int i = 0; i < 2; ++i) {
#pragma unroll
    for (int j = 0; j < 2; ++j) {
      int n = nbase + wn * 64 + j * 32 + l31;
      float bb = bias[n];
#pragma unroll
      for (int reg = 0; reg < 16; ++reg) {
        int m = wm * 64 + i * 32 + (reg & 3) + 8 * (reg >> 2) + 4 * hi;
        float v = fmaxf(acc[i][j][reg] + bb, 0.f);
        size_t off;
        if (MODE == 0)
          off = ((size_t)(b * 130 + y + 1) * 130 + (m + 1)) * 256 + n;
        else
          off = ((size_t)((b * 128 + y) * 128 + m)) * 256 + n;
        out[off] = f2bf(v);
      }
    }
  }
}

// ---- heads: h2[65536][256] x WhT[54(pad 64)][256] + bias, softmax pairs ----
__global__ __launch_bounds__(256) void heads_kernel(
    const unsigned short* __restrict__ h2,
    const unsigned short* __restrict__ WhT,
    const float* __restrict__ br, const float* __restrict__ bc,
    float* __restrict__ out) {
  __shared__ __align__(16) unsigned short As[64][264];
  const int tid = threadIdx.x;
  const int wave = tid >> 6, lane = tid & 63;
  const int quad = lane >> 4, l16 = lane & 15;
  const int pix0 = blockIdx.x * 64;
#pragma unroll
  for (int r = 0; r < 8; ++r) {
    int s = r * 256 + tid;
    int row = s >> 5, seg = s & 31;                  // 64 rows x 32 x 16B
    *(uint4*)&As[row][seg * 8] =
        *(const uint4*)(h2 + (size_t)(pix0 + row) * 256 + seg * 8);
  }
  __syncthreads();
  f32x4 acc[4] = {};
#pragma unroll
  for (int ks = 0; ks < 8; ++ks) {
    bf16x8 af = *(const bf16x8*)&As[wave * 16 + l16][ks * 32 + quad * 8];
#pragma unroll
    for (int j = 0; j < 4; ++j) {
      bf16x8 bfr = *(const bf16x8*)(WhT + (size_t)(j * 16 + l16) * 256 + ks * 32 + quad * 8);
      acc[j] = __builtin_amdgcn_mfma_f32_16x16x32_bf16(af, bfr, acc[j], 0, 0, 0);
    }
  }
#pragma unroll
  for (int j = 0; j < 4; ++j) {
    int n = j * 16 + l16;                            // head channel (cls 0-17, reg 18-53)
    float bias = 0.f;
    if (n < 18) bias = bc[n];
    else if (n < 54) bias = br[n - 18];
#pragma unroll
    for (int r = 0; r < 4; ++r) {
      int p = pix0 + wave * 16 + quad * 4 + r;       // pixel
      float v = acc[j][r] + bias;
      float partner = __shfl_xor(v, 1);              // cls pair (even,odd lanes)
      if (n < 18) {
        float mx = fmaxf(v, partner);
        float e0 = __expf(v - mx), e1 = __expf(partner - mx);
        int a = n >> 1, sl = n & 1;
        out[(size_t)p * 54 + a * 6 + sl] = e0 / (e0 + e1);
      } else if (n < 54) {
        int rr = n - 18, a = rr >> 2, sl = (rr & 3) + 2;
        out[(size_t)p * 54 + a * 6 + sl] = v;
      }
    }
  }
}

// ---------------------------------------------------------------------------
extern "C" void kernel_launch(void* const* d_in, const int* in_sizes, int n_in,
                              void* d_out, int out_size, void* d_ws, size_t ws_size,
                              hipStream_t stream) {
  const float* x  = (const float*)d_in[0];
  const float* W1 = (const float*)d_in[1];
  const float* b1 = (const float*)d_in[2];
  const float* W2 = (const float*)d_in[3];
  const float* b2 = (const float*)d_in[4];
  const float* Wr = (const float*)d_in[5];
  const float* br = (const float*)d_in[6];
  const float* Wc = (const float*)d_in[7];
  const float* bc = (const float*)d_in[8];
  float* out = (float*)d_out;

  // workspace carve-up (bytes)
  constexpr size_t XPAD_B  = 4ull * 130 * 130 * 512 * 2;   //  69,222,400
  constexpr size_t H1PAD_B = 4ull * 130 * 130 * 256 * 2;   //  34,611,200
  constexpr size_t H2_B    = 4ull * 128 * 128 * 256 * 2;   //  33,554,432
  constexpr size_t W1T_B   = 9ull * 256 * 512 * 2;         //   2,359,296
  constexpr size_t W2T_B   = 9ull * 256 * 256 * 2;         //   1,179,648
  char* ws = (char*)d_ws;
  unsigned short* x_pad  = (unsigned short*)(ws);
  unsigned short* h1_pad = (unsigned short*)(ws + XPAD_B);
  unsigned short* h2     = (unsigned short*)(ws + XPAD_B + H1PAD_B);
  unsigned short* W1T    = (unsigned short*)(ws + XPAD_B + H1PAD_B + H2_B);
  unsigned short* W2T    = (unsigned short*)(ws + XPAD_B + H1PAD_B + H2_B + W1T_B);
  unsigned short* WhT    = (unsigned short*)(ws + XPAD_B + H1PAD_B + H2_B + W1T_B + W2T_B);

  // zero the padded head-weight block (rows 54..63 are read by MFMA)
  hipMemsetAsync(WhT, 0, 64ull * 256 * 2, stream);
  // weight repacks (B^T, bf16)
  transpose_cvt<<<dim3(16, 8, 9), dim3(32, 8), 0, stream>>>(W1, W1T, 512, 256);
  transpose_cvt<<<dim3(8, 8, 9),  dim3(32, 8), 0, stream>>>(W2, W2T, 256, 256);
  transpose_cvt<<<dim3(8, 1, 1),  dim3(32, 8), 0, stream>>>(Wc, WhT, 256, 18);
  transpose_cvt<<<dim3(8, 2, 1),  dim3(32, 8), 0, stream>>>(Wr, WhT + 18 * 256, 256, 36);
  // input pad+convert, h1 halo zero
  convert_x<<<16900, 256, 0, stream>>>(x, x_pad);
  zero_h1_borders<<<8450, 256, 0, stream>>>(h1_pad);
  // conv1: 512x130x130 bf16 -> h1_pad ; conv2: -> h2 flat
  conv3x3<512, 0><<<dim3(512, 2), 256, 0, stream>>>(x_pad, W1T, b1, h1_pad);
  conv3x3<256, 1><<<dim3(512, 2), 256, 0, stream>>>(h1_pad, W2T, b2, h2);
  // 1x1 heads + softmax + interleave
  heads_kernel<<<1024, 256, 0, stream>>>(h2, WhT, br, bc, out);
}